// Round 13
// baseline (208.217 us; speedup 1.0000x reference)
//
#include <hip/hip_runtime.h>
#include <hip/hip_bf16.h>

// ============================================================================
// B=512, M=40, D=64. Three bilinear layers (200 outputs each):
//   out[o,d] = relu(bias[o] + sum_c W[o,c]*U[c,d]), U[(m,n),d] = x[m,d]*h[n,d]
// Per b: GEMM C[208,64] = W[208,K] x U[K,64] bf16, K=1600/4000/4000.
// R13 = R12 schedule (8 U-slabs, 4-kstep phases, raw s_barrier+lgkmcnt only)
// with PRODUCER/CONSUMER WAVE SPECIALIZATION:
//   waves 0-5: consumers. wn=wv&1 (batch), cm=wv>>1: m-tiles 0-4 / 5-8 / 9-12
//     (A=5/4/4, tiles UNIQUE per wave -> A-frag L1 traffic halved). K-loop
//     stream is nearly pure ds_read_b64 + MFMA.
//   waves 6-7: producers. pp=wv&1; producer pp builds k-slots 16pp..16pp+15
//     (4 groups of 4) for BOTH batches each kstep - all build VALU lives here.
//   wv mod 4 SIMD mapping pairs each producer with a consumer (m114 overlap).
// U XOR position perm (R5-verified): logical uint u of row d at dword
//   2*((u>>1)^((d>>1)&7)) + (u&1). Producer group g writes uints 8pp+2g(+1)
//   -> uint2 at dword 2*((4pp+g)^hdw)  (same involution consumers read).
// ============================================================================

typedef float f32x4 __attribute__((ext_vector_type(4)));
typedef short bf16x8 __attribute__((ext_vector_type(8)));
typedef unsigned int uint;

#define XS_STR 44     // bf16; 88B rows
#define HS_STR 108    // bf16; 216B rows

struct LDSState {
    __hip_bfloat16 xs[2][64][XS_STR];     // [bb][d][m]         11264 B
    __hip_bfloat16 hs[2][2][64][HS_STR];  // [pp][bb][d][n]     55296 B
    uint U[8][2][64][16];                 // [slab][bb][d][pos] 65536 B
};                                        // total 132096 B -> 1 block/CU

static __device__ __forceinline__ float bflo(uint u) {
    uint v = u << 16; return __builtin_bit_cast(float, v);
}
static __device__ __forceinline__ float bfhi(uint u) {
    uint v = u & 0xffff0000u; return __builtin_bit_cast(float, v);
}
static __device__ __forceinline__ uint pk_bf16(float a, float b) {
    uint r; asm("v_cvt_pk_bf16_f32 %0, %1, %2" : "=v"(r) : "v"(a), "v"(b));
    return r;
}

#define PHASE_BAR() do {                                   \
    asm volatile("s_waitcnt lgkmcnt(0)" ::: "memory");     \
    __builtin_amdgcn_sched_barrier(0);                     \
    __builtin_amdgcn_s_barrier();                          \
    __builtin_amdgcn_sched_barrier(0);                     \
} while (0)

template<int DIV, int NK, int HASH, int ROWLO, int ROWOFF, int HSTR, int A, int CONS>
__device__ __forceinline__ void layer_core(
    LDSState* L, const bf16x8* __restrict__ wpk, const float* __restrict__ bias,
    const __hip_bfloat16* __restrict__ h0, const __hip_bfloat16* __restrict__ h1,
    int dstpp, float* outb0, float* outb1, int tid, int mt0)
{
    const int lane = tid & 63;
    const int wv = tid >> 6, wn = wv & 1;    // consumers: batch; producers: pp
    const int q = lane >> 4, lr = lane & 15, d = lane;

    // ---- consumer read bases (R5-verified perm); slab stride 2048 dw ----
    const int hdr = (lr >> 1) & 7;
    const uint* ub  = &L->U[0][0][0][0] + wn * 1024;
    const uint* roA = ub + (lr * 16 + 2 * ((2 * q) ^ hdr));
    const uint* roB = ub + (lr * 16 + 2 * ((2 * q + 1) ^ hdr));

    // ---- producer write base ----
    const int hdw = (d >> 1) & 7;
    uint* wbp = &L->U[0][0][d][0];
    const int pp = wv & 1;                   // producer id (wv 6->0, 7->1)

    const __hip_bfloat16* xb0 = &L->xs[0][d][0];
    const __hip_bfloat16* xb1 = &L->xs[1][d][0];
    const __hip_bfloat16* hb0 = h0 + d * HSTR;
    const __hip_bfloat16* hb1 = h1 + d * HSTR;

    f32x4 acc[A][4];
    if constexpr (CONS) {
        #pragma unroll
        for (int mi = 0; mi < A; ++mi)
            #pragma unroll
            for (int nj = 0; nj < 4; ++nj)
                acc[mi][nj] = {0.f, 0.f, 0.f, 0.f};
    }

    // ---- producer build state: 4 groups, slots c0 = 32*bk + 16pp + 4g ----
    int pm[4], pn[4];
    #pragma unroll
    for (int g = 0; g < 4; ++g) {
        const int c0 = 16 * pp + 4 * g;
        pm[g] = c0 / DIV; pn[g] = c0 % DIV;
    }
    int bk = 0;
    auto build = [&]() {
        if (bk < NK) {
            const int slab_dw = (bk & 7) * 2048;
            #pragma unroll
            for (int g = 0; g < 4; ++g) {
                float xf0 = __bfloat162float(xb0[pm[g]]);
                float xf1 = __bfloat162float(xb1[pm[g]]);
                uint2 ha = *(const uint2*)(hb0 + pn[g]);
                uint2 hc = *(const uint2*)(hb1 + pn[g]);
                uint2 w0, w1;
                w0.x = pk_bf16(xf0 * bflo(ha.x), xf0 * bfhi(ha.x));
                w0.y = pk_bf16(xf0 * bflo(ha.y), xf0 * bfhi(ha.y));
                w1.x = pk_bf16(xf1 * bflo(hc.x), xf1 * bfhi(hc.x));
                w1.y = pk_bf16(xf1 * bflo(hc.y), xf1 * bfhi(hc.y));
                const int pos = 2 * ((4 * pp + g) ^ hdw);
                *(uint2*)(wbp + slab_dw + pos)        = w0;
                *(uint2*)(wbp + slab_dw + 1024 + pos) = w1;
                pn[g] += 32;
                if (pn[g] >= DIV) { pn[g] -= DIV; ++pm[g]; }
            }
            ++bk;
        }
    };

    auto consume = [&](int slab_dw, bf16x8* f) {
        bf16x8 bv[4];
        #pragma unroll
        for (int nj = 0; nj < 4; ++nj) {
            union { uint2 u2[2]; bf16x8 v; } t;
            t.u2[0] = *(const uint2*)(roA + slab_dw + nj * 256);
            t.u2[1] = *(const uint2*)(roB + slab_dw + nj * 256);
            bv[nj] = t.v;
        }
        #pragma unroll
        for (int mi = 0; mi < A; ++mi)
            #pragma unroll
            for (int nj = 0; nj < 4; ++nj)
                acc[mi][nj] = __builtin_amdgcn_mfma_f32_16x16x32_bf16(
                    f[mi], bv[nj], acc[mi][nj], 0, 0, 0);
    };

    const bf16x8* pw = wpk + (size_t)mt0 * NK * 64 + lane;
    auto loadf = [&](bf16x8* f, int s) {
        if (s < NK) {
            #pragma unroll
            for (int mi = 0; mi < A; ++mi)
                f[mi] = pw[(size_t)mi * NK * 64 + (size_t)s * 64];
        }
    };

    bf16x8 a0[A], a1[A], a2[A], a3[A];
    if constexpr (CONS) {
        loadf(a0, 0); loadf(a1, 1); loadf(a2, 2); loadf(a3, 3);
    } else {
        build(); build(); build(); build();     // ksteps 0-3 -> slabs 0-3
    }
    __syncthreads();

    #pragma unroll 1
    for (int s = 0; s + 8 <= NK; s += 8) {
        // phase A: consume ksteps s..s+3 (slabs 0-3) / build s+4..s+7 (4-7)
        if constexpr (CONS) {
            consume(0,    a0); loadf(a0, s + 4);
            consume(2048, a1); loadf(a1, s + 5);
            consume(4096, a2); loadf(a2, s + 6);
            consume(6144, a3); loadf(a3, s + 7);
        } else {
            build(); build(); build(); build();
        }
        PHASE_BAR();
        // phase B: consume s+4..s+7 (slabs 4-7) / build s+8..s+11 (0-3)
        if constexpr (CONS) {
            consume(8192,  a0); loadf(a0, s + 8);
            consume(10240, a1); loadf(a1, s + 9);
            consume(12288, a2); loadf(a2, s + 10);
            consume(14336, a3); loadf(a3, s + 11);
        } else {
            build(); build(); build(); build();
        }
        PHASE_BAR();
    }
    // tail: REM = NK % 8 ksteps in slabs 0..REM-1 (already built in last
    // phase B, visible after its barrier). REM = 2 (NK=50) or 5 (NK=125).
    constexpr int REM = NK % 8;
    if constexpr (REM == 2) {
        if constexpr (CONS) { consume(0, a0); consume(2048, a1); }
    } else if constexpr (REM == 5) {
        if constexpr (CONS) {
            consume(0, a0);
            loadf(a0, NK - 1);            // frag for final kstep
            consume(2048, a1);
            consume(4096, a2);
            consume(6144, a3);
        } else {
            build();                      // kstep NK-1 -> slab 4
        }
        PHASE_BAR();
        if constexpr (CONS) consume(8192, a0);
    }

    // ---- epilogue (consumers): C/D layout row = 4q+reg, col = lr ----
    if constexpr (CONS) {
        float* outp = wn ? outb1 : outb0;
        #pragma unroll
        for (int mi = 0; mi < A; ++mi) {
            const int mt = mt0 + mi;
            #pragma unroll
            for (int reg = 0; reg < 4; ++reg) {
                const int o = 16 * mt + 4 * q + reg;
                if (o < 200) {
                    const float bs = bias[o];
                    float r0 = fmaxf(acc[mi][0][reg] + bs, 0.f);
                    float r1 = fmaxf(acc[mi][1][reg] + bs, 0.f);
                    float r2 = fmaxf(acc[mi][2][reg] + bs, 0.f);
                    float r3 = fmaxf(acc[mi][3][reg] + bs, 0.f);
                    if (HASH && o < 100) {
                        L->hs[dstpp][wn][ 0 + lr][o] = __float2bfloat16(r0);
                        L->hs[dstpp][wn][16 + lr][o] = __float2bfloat16(r1);
                        L->hs[dstpp][wn][32 + lr][o] = __float2bfloat16(r2);
                        L->hs[dstpp][wn][48 + lr][o] = __float2bfloat16(r3);
                    }
                    if (o >= ROWLO) {
                        float sv = (r0 + r1) + (r2 + r3);
                        sv += __shfl_xor(sv, 1, 64);
                        sv += __shfl_xor(sv, 2, 64);
                        sv += __shfl_xor(sv, 4, 64);
                        sv += __shfl_xor(sv, 8, 64);
                        if (lr == 0) outp[ROWOFF + (o - ROWLO)] = sv;
                    }
                }
            }
        }
    }
    __syncthreads();
}

template<int A, int CONS>
__device__ __forceinline__ void run_layers(
    LDSState* L, const bf16x8* w1p, const bf16x8* w2p, const bf16x8* w3p,
    const float* b1, const float* b2, const float* b3,
    float* outb0, float* outb1, int tid, int mt0)
{
    layer_core< 40,  50, 1, 100,   0, XS_STR, A, CONS>(L, w1p, b1,
        &L->xs[0][0][0], &L->xs[1][0][0], 0, outb0, outb1, tid, mt0);
    layer_core<100, 125, 1, 100, 100, HS_STR, A, CONS>(L, w2p, b2,
        &L->hs[0][0][0][0], &L->hs[0][1][0][0], 1, outb0, outb1, tid, mt0);
    layer_core<100, 125, 0,   0, 200, HS_STR, A, CONS>(L, w3p, b3,
        &L->hs[1][0][0][0], &L->hs[1][1][0][0], 0, outb0, outb1, tid, mt0);
}

__global__ __launch_bounds__(512, 2)
void fused_mfma(const float* __restrict__ x,
                const bf16x8* __restrict__ wpk,
                const float* __restrict__ b1, const float* __restrict__ b2,
                const float* __restrict__ b3, float* __restrict__ out) {
    __shared__ LDSState L;
    const int tid = threadIdx.x;
    const int bi  = blockIdx.x;

    // stage x (2 b's), fp32 -> bf16, transposed to [d][m]
    const float* xg = x + (size_t)(2 * bi) * 2560;
    for (int i = tid; i < 5120; i += 512) {
        int bb = (i >= 2560) ? 1 : 0;
        int r  = i - bb * 2560;
        L.xs[bb][r & 63][r >> 6] = __float2bfloat16(xg[(size_t)bb * 2560 + r]);
    }
    __syncthreads();

    float* outb0 = out + (size_t)(2 * bi + 0) * 400;
    float* outb1 = out + (size_t)(2 * bi + 1) * 400;

    const bf16x8* w1p = wpk;              // 13*50*64  = 41600 frags
    const bf16x8* w2p = wpk + 41600;      // 13*125*64 = 104000
    const bf16x8* w3p = wpk + 145600;

    const int wv = tid >> 6;
    if (wv < 6) {
        const int cm = wv >> 1;           // consumer m-group
        if (cm == 0)
            run_layers<5, 1>(&L, w1p, w2p, w3p, b1, b2, b3, outb0, outb1, tid, 0);
        else if (cm == 1)
            run_layers<4, 1>(&L, w1p, w2p, w3p, b1, b2, b3, outb0, outb1, tid, 5);
        else
            run_layers<4, 1>(&L, w1p, w2p, w3p, b1, b2, b3, outb0, outb1, tid, 9);
    } else {
        run_layers<1, 0>(&L, w1p, w2p, w3p, b1, b2, b3, outb0, outb1, tid, 0);
    }
}

// ---------------------------------------------------------------------------
// Prepass: repack W fp32 -> bf16 frag-contiguous. Element c = one lane's
// bf16x8: c = layerbase + (mt*NK + s)*64 + lane, holding
// W[16*mt + (lane&15), 32*s + 8*(lane>>4) .. +8]  (rows >= 200 zero).
// ---------------------------------------------------------------------------
__global__ void convert_pack(const float* __restrict__ w1, const float* __restrict__ w2,
                             const float* __restrict__ w3, uint4* __restrict__ outp) {
    int c = blockIdx.x * 256 + threadIdx.x;
    if (c >= 249600) return;
    const float* src; int K, base;
    if (c < 41600)       { src = w1; K = 1600; base = c; }
    else if (c < 145600) { src = w2; K = 4000; base = c - 41600; }
    else                 { src = w3; K = 4000; base = c - 145600; }
    const int NS   = K / 32;
    const int lane = base & 63;
    const int t    = base >> 6;
    const int mt   = t / NS;
    const int s    = t - mt * NS;
    const int row  = 16 * mt + (lane & 15);
    const int k0   = 32 * s + 8 * (lane >> 4);
    uint o[4];
    if (row < 200) {
        const float* p = src + (size_t)row * K + k0;
        #pragma unroll
        for (int j = 0; j < 4; ++j) {
            __hip_bfloat16 lo = __float2bfloat16(p[2 * j]);
            __hip_bfloat16 hi = __float2bfloat16(p[2 * j + 1]);
            o[j] = (uint)__builtin_bit_cast(unsigned short, lo)
                 | ((uint)__builtin_bit_cast(unsigned short, hi) << 16);
        }
    } else {
        #pragma unroll
        for (int j = 0; j < 4; ++j) o[j] = 0u;
    }
    uint4 v; v.x = o[0]; v.y = o[1]; v.z = o[2]; v.w = o[3];
    outp[c] = v;
}

// ---------------------------------------------------------------------------
// Fallback (fp32 VALU kernel) if ws too small.
// ---------------------------------------------------------------------------
__global__ __launch_bounds__(512, 1)
void fused_bilinear_kernel(const float* __restrict__ x,
                           const float* __restrict__ w1, const float* __restrict__ b1,
                           const float* __restrict__ w2, const float* __restrict__ b2,
                           const float* __restrict__ w3, const float* __restrict__ b3,
                           float* __restrict__ out) {
    const int b   = blockIdx.x;
    const int tid = threadIdx.x;
    const int d   = tid & 63;
    const int wv  = tid >> 6;

    __shared__ float xs[40][64];
    __shared__ float hs[100][64];

    const float* xb = x + (size_t)b * 40 * 64;
    for (int i = tid; i < 40 * 64; i += 512) ((float*)xs)[i] = xb[i];
    __syncthreads();

    float xr[40];
    #pragma unroll
    for (int m = 0; m < 40; ++m) xr[m] = xs[m][d];
    float hr[100];
    const int o0 = __builtin_amdgcn_readfirstlane(wv * 25);

    for (int oi = 0; oi < 25; ++oi) {
        const int o = o0 + oi;
        const float* __restrict__ wrow = w1 + (size_t)o * 1600;
        float s = b1[o];
        for (int m = 0; m < 40; ++m) {
            const float* __restrict__ wm = wrow + m * 40;
            float a0 = 0.f, a1 = 0.f, a2 = 0.f, a3 = 0.f;
            #pragma unroll
            for (int n = 0; n < 40; n += 4) {
                a0 = fmaf(wm[n + 0], xr[n + 0], a0);
                a1 = fmaf(wm[n + 1], xr[n + 1], a1);
                a2 = fmaf(wm[n + 2], xr[n + 2], a2);
                a3 = fmaf(wm[n + 3], xr[n + 3], a3);
            }
            s = fmaf(xs[m][d], (a0 + a1) + (a2 + a3), s);
        }
        s = fmaxf(s, 0.f);
        if (o < 100) hs[o][d] = s;
        else {
            float r = s;
            #pragma unroll
            for (int off = 32; off > 0; off >>= 1) r += __shfl_xor(r, off, 64);
            if (d == 0) out[(size_t)b * 400 + (o - 100)] = r;
        }
    }
    __syncthreads();
    #pragma unroll
    for (int n = 0; n < 100; ++n) hr[n] = hs[n][d];
    __syncthreads();

    for (int oi = 0; oi < 25; ++oi) {
        const int o = o0 + oi;
        const float* __restrict__ wrow = w2 + (size_t)o * 4000;
        float s = b2[o];
        for (int m = 0; m < 40; ++m) {
            const float* __restrict__ wm = wrow + m * 100;
            float a0 = 0.f, a1 = 0.f, a2 = 0.f, a3 = 0.f;
            #pragma unroll
            for (int n = 0; n < 100; n += 4) {
                a0 = fmaf(wm[n + 0], hr[n + 0], a0);
                a1 = fmaf(wm[n + 1], hr[n + 1], a1);
                a2 = fmaf(wm[n + 2], hr[n + 2], a2);
                a3 = fmaf(wm[n + 3], hr[n + 3], a3);
            }
            s = fmaf(xs[m][d], (a0 + a1) + (a2 + a3), s);
        }
        s = fmaxf(s, 0.f);
        if (o < 100) hs[o][d] = s;
        else {
            float r = s;
            #pragma unroll
            for (int off = 32; off > 0; off >>= 1) r += __shfl_xor(r, off, 64);
            if (d == 0) out[(size_t)b * 400 + 100 + (o - 100)] = r;
        }
    }
    __syncthreads();
    #pragma unroll
    for (int n = 0; n < 100; ++n) hr[n] = hs[n][d];

    for (int oi = 0; oi < 25; ++oi) {
        const int o = o0 + oi;
        const float* __restrict__ wrow = w3 + (size_t)o * 4000;
        float s = b3[o];
        for (int m = 0; m < 40; ++m) {
            const float* __restrict__ wm = wrow + m * 100;
            float a0 = 0.f, a1 = 0.f, a2 = 0.f, a3 = 0.f;
            #pragma unroll
            for (int n = 0; n < 100; n += 4) {
                a0 = fmaf(wm[n + 0], hr[n + 0], a0);
                a1 = fmaf(wm[n + 1], hr[n + 1], a1);
                a2 = fmaf(wm[n + 2], hr[n + 2], a2);
                a3 = fmaf(wm[n + 3], hr[n + 3], a3);
            }
            s = fmaf(xs[m][d], (a0 + a1) + (a2 + a3), s);
        }
        s = fmaxf(s, 0.f);
        float r = s;
        #pragma unroll
        for (int off = 32; off > 0; off >>= 1) r += __shfl_xor(r, off, 64);
        if (d == 0) out[(size_t)b * 400 + 200 + o] = r;
    }
}

extern "C" void kernel_launch(void* const* d_in, const int* in_sizes, int n_in,
                              void* d_out, int out_size, void* d_ws, size_t ws_size,
                              hipStream_t stream) {
    const float* x  = (const float*)d_in[0];
    const float* w1 = (const float*)d_in[1];
    const float* b1 = (const float*)d_in[2];
    const float* w2 = (const float*)d_in[3];
    const float* b2 = (const float*)d_in[4];
    const float* w3 = (const float*)d_in[5];
    const float* b3 = (const float*)d_in[6];
    float* out = (float*)d_out;

    if (ws_size >= 249600u * 16u) {
        uint4* wp = (uint4*)d_ws;
        convert_pack<<<dim3(975), dim3(256), 0, stream>>>(w1, w2, w3, wp);
        fused_mfma<<<dim3(256), dim3(512), 0, stream>>>(
            x, (const bf16x8*)wp, b1, b2, b3, out);
    } else {
        fused_bilinear_kernel<<<dim3(512), dim3(512), 0, stream>>>(
            x, w1, b1, w2, b2, w3, b3, out);
    }
}

// Round 14
// 158.752 us; speedup vs baseline: 1.3116x; 1.3116x over previous
//
#include <hip/hip_runtime.h>
#include <hip/hip_bf16.h>

// ============================================================================
// B=512, M=40, D=64. Three bilinear layers (200 outputs each):
//   out[o,d] = relu(bias[o] + sum_c W[o,c]*U[c,d]), U[(m,n),d] = x[m,d]*h[n,d]
// Per b: GEMM C[208,64] = W[208,K] x U[K,64] bf16, K=1600/4000/4000.
// R12 (BEST, restored): R5 structure with 4-kstep phases and 8 U-slabs:
//   - 1 barrier per 4 ksteps
//   - A-frag slot reloaded right after its consume for kstep+8 -> full-phase
//     latency cover (~1200 cyc >> L2 latency)
//   - build-to-consume slack: slab written 1-2 phases before its read
// Block = 2 batches, grid 256 (1/CU), 8 waves = 4 gm (m-tiles 4/3/3/3) x 2 wn.
// U XOR position perm (R5-verified): logical uint u of row d at dword
//   2*((u>>1)^((d>>1)&7)) + (u&1). Raw s_barrier + lgkmcnt(0) only (A-frag
//   global loads are wave-private, fly across barriers - no vmcnt drain).
// ============================================================================

typedef float f32x4 __attribute__((ext_vector_type(4)));
typedef short bf16x8 __attribute__((ext_vector_type(8)));
typedef unsigned int uint;

#define XS_STR 44     // bf16; 88B rows
#define HS_STR 108    // bf16; 216B rows

struct LDSState {
    __hip_bfloat16 xs[2][64][XS_STR];     // [bb][d][m]         11264 B
    __hip_bfloat16 hs[2][2][64][HS_STR];  // [pp][bb][d][n]     55296 B
    uint U[8][2][64][16];                 // [slab][bb][d][pos] 65536 B
};                                        // total 132096 B -> 1 block/CU

static __device__ __forceinline__ float bflo(uint u) {
    uint v = u << 16; return __builtin_bit_cast(float, v);
}
static __device__ __forceinline__ float bfhi(uint u) {
    uint v = u & 0xffff0000u; return __builtin_bit_cast(float, v);
}
static __device__ __forceinline__ uint pk_bf16(float a, float b) {
    uint r; asm("v_cvt_pk_bf16_f32 %0, %1, %2" : "=v"(r) : "v"(a), "v"(b));
    return r;
}

#define PHASE_BAR() do {                                   \
    asm volatile("s_waitcnt lgkmcnt(0)" ::: "memory");     \
    __builtin_amdgcn_sched_barrier(0);                     \
    __builtin_amdgcn_s_barrier();                          \
    __builtin_amdgcn_sched_barrier(0);                     \
} while (0)

template<int DIV, int NK, int HASH, int ROWLO, int ROWOFF, int HSTR, int A>
__device__ __forceinline__ void layer_core(
    LDSState* L, const bf16x8* __restrict__ wpk, const float* __restrict__ bias,
    const __hip_bfloat16* __restrict__ h0, const __hip_bfloat16* __restrict__ h1,
    int dstpp, float* outb0, float* outb1, int tid, int mt0)
{
    const int lane = tid & 63;
    const int wv = tid >> 6, wn = wv & 1;
    const int q = lane >> 4, lr = lane & 15, d = lane;

    // consume read bases (R5-verified perm); slab stride 2048 dwords
    const int hdr = (lr >> 1) & 7;
    const uint* ub  = &L->U[0][0][0][0] + wn * 1024;
    const uint* roA = ub + (lr * 16 + 2 * ((2 * q) ^ hdr));
    const uint* roB = ub + (lr * 16 + 2 * ((2 * q + 1) ^ hdr));

    // build write base: wave wv owns k-slots 4wv..4wv+3 (uints 2wv,2wv+1)
    const int hdw = (d >> 1) & 7;
    uint* wb = &L->U[0][0][d][0] + 2 * (wv ^ hdw);

    const __hip_bfloat16* xb0 = &L->xs[0][d][0];
    const __hip_bfloat16* xb1 = &L->xs[1][d][0];
    const __hip_bfloat16* hb0 = h0 + d * HSTR;
    const __hip_bfloat16* hb1 = h1 + d * HSTR;

    f32x4 acc[A][4];
    #pragma unroll
    for (int mi = 0; mi < A; ++mi)
        #pragma unroll
        for (int nj = 0; nj < 4; ++nj)
            acc[mi][nj] = {0.f, 0.f, 0.f, 0.f};

    // build state machine: kstep bk covers k-slots c0 = 32*bk + 4*wv .. +3
    int bm = (4 * wv) / DIV;
    int bn = (4 * wv) % DIV;
    int bk = 0;
    auto build = [&]() {
        if (bk < NK) {
            const int slab_dw = (bk & 7) * 2048;
            float xf0 = __bfloat162float(xb0[bm]);
            float xf1 = __bfloat162float(xb1[bm]);
            uint2 ha = *(const uint2*)(hb0 + bn);
            uint2 hc = *(const uint2*)(hb1 + bn);
            uint2 w0, w1;
            w0.x = pk_bf16(xf0 * bflo(ha.x), xf0 * bfhi(ha.x));
            w0.y = pk_bf16(xf0 * bflo(ha.y), xf0 * bfhi(ha.y));
            w1.x = pk_bf16(xf1 * bflo(hc.x), xf1 * bfhi(hc.x));
            w1.y = pk_bf16(xf1 * bflo(hc.y), xf1 * bfhi(hc.y));
            *(uint2*)(wb + slab_dw)        = w0;
            *(uint2*)(wb + slab_dw + 1024) = w1;
            bn += 32;
            if (bn >= DIV) { bn -= DIV; ++bm; }
            ++bk;
        }
    };

    auto consume = [&](int slab_dw, bf16x8* f) {
        bf16x8 bv[4];
        #pragma unroll
        for (int nj = 0; nj < 4; ++nj) {
            union { uint2 u2[2]; bf16x8 v; } t;
            t.u2[0] = *(const uint2*)(roA + slab_dw + nj * 256);
            t.u2[1] = *(const uint2*)(roB + slab_dw + nj * 256);
            bv[nj] = t.v;
        }
        #pragma unroll
        for (int mi = 0; mi < A; ++mi)
            #pragma unroll
            for (int nj = 0; nj < 4; ++nj)
                acc[mi][nj] = __builtin_amdgcn_mfma_f32_16x16x32_bf16(
                    f[mi], bv[nj], acc[mi][nj], 0, 0, 0);
    };

    const bf16x8* pw = wpk + (size_t)mt0 * NK * 64 + lane;
    auto loadf = [&](bf16x8* f, int s) {
        if (s < NK) {
            #pragma unroll
            for (int mi = 0; mi < A; ++mi)
                f[mi] = pw[(size_t)mi * NK * 64 + (size_t)s * 64];
        }
    };

    bf16x8 a0[A], a1[A], a2[A], a3[A], b0[A], b1[A], b2[A], b3[A];
    loadf(a0, 0); loadf(a1, 1); loadf(a2, 2); loadf(a3, 3);
    loadf(b0, 4); loadf(b1, 5); loadf(b2, 6); loadf(b3, 7);
    build(); build(); build(); build();     // ksteps 0-3 -> slabs 0-3
    __syncthreads();

    #pragma unroll 1
    for (int s = 0; s + 8 <= NK; s += 8) {
        // phase A: consume ksteps s..s+3 (slabs 0-3); build s+4..s+7 (4-7)
        consume(0 * 2048, a0); loadf(a0, s + 8);
        consume(1 * 2048, a1); loadf(a1, s + 9);
        consume(2 * 2048, a2); loadf(a2, s + 10);
        consume(3 * 2048, a3); loadf(a3, s + 11);
        build(); build(); build(); build();
        PHASE_BAR();
        // phase B: consume s+4..s+7 (slabs 4-7); build s+8..s+11 (slabs 0-3)
        consume(4 * 2048, b0); loadf(b0, s + 12);
        consume(5 * 2048, b1); loadf(b1, s + 13);
        consume(6 * 2048, b2); loadf(b2, s + 14);
        consume(7 * 2048, b3); loadf(b3, s + 15);
        build(); build(); build(); build();
        PHASE_BAR();
    }
    // tail: REM = NK % 8 ksteps remain, in slabs 0..REM-1 (built; frags in
    // a0..a3 / b0). REM = 2 (NK=50) or 5 (NK=125).
    constexpr int REM = NK % 8;
    if constexpr (REM >= 1) consume(0 * 2048, a0);
    if constexpr (REM >= 2) consume(1 * 2048, a1);
    if constexpr (REM >= 3) consume(2 * 2048, a2);
    if constexpr (REM >= 4) consume(3 * 2048, a3);
    if constexpr (REM == 5) {
        build();                 // kstep NK-1 -> slab 4
        PHASE_BAR();
        consume(4 * 2048, b0);
    }

    // epilogue: C/D layout row = 4q+reg, col = lr (m89-verified)
    float* outp = wn ? outb1 : outb0;
    #pragma unroll
    for (int mi = 0; mi < A; ++mi) {
        const int mt = mt0 + mi;
        #pragma unroll
        for (int reg = 0; reg < 4; ++reg) {
            const int o = 16 * mt + 4 * q + reg;
            if (o < 200) {
                const float bs = bias[o];
                float r0 = fmaxf(acc[mi][0][reg] + bs, 0.f);
                float r1 = fmaxf(acc[mi][1][reg] + bs, 0.f);
                float r2 = fmaxf(acc[mi][2][reg] + bs, 0.f);
                float r3 = fmaxf(acc[mi][3][reg] + bs, 0.f);
                if (HASH && o < 100) {
                    L->hs[dstpp][wn][ 0 + lr][o] = __float2bfloat16(r0);
                    L->hs[dstpp][wn][16 + lr][o] = __float2bfloat16(r1);
                    L->hs[dstpp][wn][32 + lr][o] = __float2bfloat16(r2);
                    L->hs[dstpp][wn][48 + lr][o] = __float2bfloat16(r3);
                }
                if (o >= ROWLO) {
                    float sv = (r0 + r1) + (r2 + r3);
                    sv += __shfl_xor(sv, 1, 64);
                    sv += __shfl_xor(sv, 2, 64);
                    sv += __shfl_xor(sv, 4, 64);
                    sv += __shfl_xor(sv, 8, 64);
                    if (lr == 0) outp[ROWOFF + (o - ROWLO)] = sv;
                }
            }
        }
    }
    __syncthreads();
}

template<int A>
__device__ __forceinline__ void run_layers(
    LDSState* L, const bf16x8* w1p, const bf16x8* w2p, const bf16x8* w3p,
    const float* b1, const float* b2, const float* b3,
    float* outb0, float* outb1, int tid, int mt0)
{
    layer_core< 40,  50, 1, 100,   0, XS_STR, A>(L, w1p, b1,
        &L->xs[0][0][0], &L->xs[1][0][0], 0, outb0, outb1, tid, mt0);
    layer_core<100, 125, 1, 100, 100, HS_STR, A>(L, w2p, b2,
        &L->hs[0][0][0][0], &L->hs[0][1][0][0], 1, outb0, outb1, tid, mt0);
    layer_core<100, 125, 0,   0, 200, HS_STR, A>(L, w3p, b3,
        &L->hs[1][0][0][0], &L->hs[1][1][0][0], 0, outb0, outb1, tid, mt0);
}

__global__ __launch_bounds__(512, 2)
void fused_mfma(const float* __restrict__ x,
                const bf16x8* __restrict__ wpk,
                const float* __restrict__ b1, const float* __restrict__ b2,
                const float* __restrict__ b3, float* __restrict__ out) {
    __shared__ LDSState L;
    const int tid = threadIdx.x;
    const int bi  = blockIdx.x;

    // stage x (2 b's), fp32 -> bf16, transposed to [d][m]
    const float* xg = x + (size_t)(2 * bi) * 2560;
    for (int i = tid; i < 5120; i += 512) {
        int bb = (i >= 2560) ? 1 : 0;
        int r  = i - bb * 2560;
        L.xs[bb][r & 63][r >> 6] = __float2bfloat16(xg[(size_t)bb * 2560 + r]);
    }
    __syncthreads();

    float* outb0 = out + (size_t)(2 * bi + 0) * 400;
    float* outb1 = out + (size_t)(2 * bi + 1) * 400;

    const bf16x8* w1p = wpk;              // 13*50*64  = 41600 frags
    const bf16x8* w2p = wpk + 41600;      // 13*125*64 = 104000
    const bf16x8* w3p = wpk + 145600;

    const int wm = tid >> 7;              // wave-pair id 0..3
    if (wm == 0)
        run_layers<4>(&L, w1p, w2p, w3p, b1, b2, b3, outb0, outb1, tid, 0);
    else
        run_layers<3>(&L, w1p, w2p, w3p, b1, b2, b3, outb0, outb1, tid,
                      3 * wm + 1);
}

// ---------------------------------------------------------------------------
// Prepass: repack W fp32 -> bf16 frag-contiguous. Element c = one lane's
// bf16x8: c = layerbase + (mt*NK + s)*64 + lane, holding
// W[16*mt + (lane&15), 32*s + 8*(lane>>4) .. +8]  (rows >= 200 zero).
// ---------------------------------------------------------------------------
__global__ void convert_pack(const float* __restrict__ w1, const float* __restrict__ w2,
                             const float* __restrict__ w3, uint4* __restrict__ outp) {
    int c = blockIdx.x * 256 + threadIdx.x;
    if (c >= 249600) return;
    const float* src; int K, base;
    if (c < 41600)       { src = w1; K = 1600; base = c; }
    else if (c < 145600) { src = w2; K = 4000; base = c - 41600; }
    else                 { src = w3; K = 4000; base = c - 145600; }
    const int NS   = K / 32;
    const int lane = base & 63;
    const int t    = base >> 6;
    const int mt   = t / NS;
    const int s    = t - mt * NS;
    const int row  = 16 * mt + (lane & 15);
    const int k0   = 32 * s + 8 * (lane >> 4);
    uint o[4];
    if (row < 200) {
        const float* p = src + (size_t)row * K + k0;
        #pragma unroll
        for (int j = 0; j < 4; ++j) {
            __hip_bfloat16 lo = __float2bfloat16(p[2 * j]);
            __hip_bfloat16 hi = __float2bfloat16(p[2 * j + 1]);
            o[j] = (uint)__builtin_bit_cast(unsigned short, lo)
                 | ((uint)__builtin_bit_cast(unsigned short, hi) << 16);
        }
    } else {
        #pragma unroll
        for (int j = 0; j < 4; ++j) o[j] = 0u;
    }
    uint4 v; v.x = o[0]; v.y = o[1]; v.z = o[2]; v.w = o[3];
    outp[c] = v;
}

// ---------------------------------------------------------------------------
// Fallback (fp32 VALU kernel) if ws too small.
// ---------------------------------------------------------------------------
__global__ __launch_bounds__(512, 1)
void fused_bilinear_kernel(const float* __restrict__ x,
                           const float* __restrict__ w1, const float* __restrict__ b1,
                           const float* __restrict__ w2, const float* __restrict__ b2,
                           const float* __restrict__ w3, const float* __restrict__ b3,
                           float* __restrict__ out) {
    const int b   = blockIdx.x;
    const int tid = threadIdx.x;
    const int d   = tid & 63;
    const int wv  = tid >> 6;

    __shared__ float xs[40][64];
    __shared__ float hs[100][64];

    const float* xb = x + (size_t)b * 40 * 64;
    for (int i = tid; i < 40 * 64; i += 512) ((float*)xs)[i] = xb[i];
    __syncthreads();

    float xr[40];
    #pragma unroll
    for (int m = 0; m < 40; ++m) xr[m] = xs[m][d];
    float hr[100];
    const int o0 = __builtin_amdgcn_readfirstlane(wv * 25);

    for (int oi = 0; oi < 25; ++oi) {
        const int o = o0 + oi;
        const float* __restrict__ wrow = w1 + (size_t)o * 1600;
        float s = b1[o];
        for (int m = 0; m < 40; ++m) {
            const float* __restrict__ wm = wrow + m * 40;
            float a0 = 0.f, a1 = 0.f, a2 = 0.f, a3 = 0.f;
            #pragma unroll
            for (int n = 0; n < 40; n += 4) {
                a0 = fmaf(wm[n + 0], xr[n + 0], a0);
                a1 = fmaf(wm[n + 1], xr[n + 1], a1);
                a2 = fmaf(wm[n + 2], xr[n + 2], a2);
                a3 = fmaf(wm[n + 3], xr[n + 3], a3);
            }
            s = fmaf(xs[m][d], (a0 + a1) + (a2 + a3), s);
        }
        s = fmaxf(s, 0.f);
        if (o < 100) hs[o][d] = s;
        else {
            float r = s;
            #pragma unroll
            for (int off = 32; off > 0; off >>= 1) r += __shfl_xor(r, off, 64);
            if (d == 0) out[(size_t)b * 400 + (o - 100)] = r;
        }
    }
    __syncthreads();
    #pragma unroll
    for (int n = 0; n < 100; ++n) hr[n] = hs[n][d];
    __syncthreads();

    for (int oi = 0; oi < 25; ++oi) {
        const int o = o0 + oi;
        const float* __restrict__ wrow = w2 + (size_t)o * 4000;
        float s = b2[o];
        for (int m = 0; m < 40; ++m) {
            const float* __restrict__ wm = wrow + m * 100;
            float a0 = 0.f, a1 = 0.f, a2 = 0.f, a3 = 0.f;
            #pragma unroll
            for (int n = 0; n < 100; n += 4) {
                a0 = fmaf(wm[n + 0], hr[n + 0], a0);
                a1 = fmaf(wm[n + 1], hr[n + 1], a1);
                a2 = fmaf(wm[n + 2], hr[n + 2], a2);
                a3 = fmaf(wm[n + 3], hr[n + 3], a3);
            }
            s = fmaf(xs[m][d], (a0 + a1) + (a2 + a3), s);
        }
        s = fmaxf(s, 0.f);
        if (o < 100) hs[o][d] = s;
        else {
            float r = s;
            #pragma unroll
            for (int off = 32; off > 0; off >>= 1) r += __shfl_xor(r, off, 64);
            if (d == 0) out[(size_t)b * 400 + 100 + (o - 100)] = r;
        }
    }
    __syncthreads();
    #pragma unroll
    for (int n = 0; n < 100; ++n) hr[n] = hs[n][d];

    for (int oi = 0; oi < 25; ++oi) {
        const int o = o0 + oi;
        const float* __restrict__ wrow = w3 + (size_t)o * 4000;
        float s = b3[o];
        for (int m = 0; m < 40; ++m) {
            const float* __restrict__ wm = wrow + m * 100;
            float a0 = 0.f, a1 = 0.f, a2 = 0.f, a3 = 0.f;
            #pragma unroll
            for (int n = 0; n < 100; n += 4) {
                a0 = fmaf(wm[n + 0], hr[n + 0], a0);
                a1 = fmaf(wm[n + 1], hr[n + 1], a1);
                a2 = fmaf(wm[n + 2], hr[n + 2], a2);
                a3 = fmaf(wm[n + 3], hr[n + 3], a3);
            }
            s = fmaf(xs[m][d], (a0 + a1) + (a2 + a3), s);
        }
        s = fmaxf(s, 0.f);
        float r = s;
        #pragma unroll
        for (int off = 32; off > 0; off >>= 1) r += __shfl_xor(r, off, 64);
        if (d == 0) out[(size_t)b * 400 + 200 + o] = r;
    }
}

extern "C" void kernel_launch(void* const* d_in, const int* in_sizes, int n_in,
                              void* d_out, int out_size, void* d_ws, size_t ws_size,
                              hipStream_t stream) {
    const float* x  = (const float*)d_in[0];
    const float* w1 = (const float*)d_in[1];
    const float* b1 = (const float*)d_in[2];
    const float* w2 = (const float*)d_in[3];
    const float* b2 = (const float*)d_in[4];
    const float* w3 = (const float*)d_in[5];
    const float* b3 = (const float*)d_in[6];
    float* out = (float*)d_out;

    if (ws_size >= 249600u * 16u) {
        uint4* wp = (uint4*)d_ws;
        convert_pack<<<dim3(975), dim3(256), 0, stream>>>(w1, w2, w3, wp);
        fused_mfma<<<dim3(256), dim3(512), 0, stream>>>(
            x, (const bf16x8*)wp, b1, b2, b3, out);
    } else {
        fused_bilinear_kernel<<<dim3(512), dim3(512), 0, stream>>>(
            x, w1, b1, w2, b2, w3, b3, out);
    }
}